// Round 10
// baseline (104.267 us; speedup 1.0000x reference)
//
#include <hip/hip_runtime.h>

#define HH 512
#define DD 64
#define MROWS 16
#define TPB 256
#define LP 520            // u16 pitch for 16x512 LDS tiles

typedef unsigned short u16;
typedef short s16x8 __attribute__((ext_vector_type(8)));   // 8 bf16 = 4 VGPRs
typedef float f32x4 __attribute__((ext_vector_type(4)));

#define MFMA16(A,B,C) __builtin_amdgcn_mfma_f32_16x16x32_bf16((A),(B),(C),0,0,0)

// ---- workspace layout (u16 element offsets) ----
// W2K/EFK: k-major chunks: addr = chunk*16384 + nt*512 + lane*8
//   value[j] = M[k][n], k = chunk*32 + (lane>>4)*8 + j, n = nt*16 + (lane&15)
//   (W2K: M=W2 ; EFK: M[b][a] = W2[a][b]*G[a][b], n-dim=a, k-dim=b)
// W1F: per-tile fragment-linear: nt*1024 + ks*512 + lane*8 (K=64)
// W3F: per-tile fragment-linear: ot*8192 + ks*512 + lane*8 (K=512)
#define OFF_W2K  0
#define OFF_EFK  262144
#define OFF_W1F  524288
#define OFF_W3F  557056
#define OFF_Z0B  (589824 * 2)     // byte offset of z0 (f32[512])

__device__ __forceinline__ u16 f2bf(float f) {
    unsigned u = __builtin_bit_cast(unsigned, f);
    u += 0x7fffu + ((u >> 16) & 1u);
    return (u16)(u >> 16);
}
__device__ __forceinline__ float bf2f(u16 h) {
    return __builtin_bit_cast(float, (unsigned)h << 16);
}
__device__ __forceinline__ float fast_tanh(float x) {
    float e = __expf(2.0f * x);
    return 1.0f - 2.0f * __builtin_amdgcn_rcpf(e + 1.0f);
}
__device__ __forceinline__ void gll(const u16* g, u16* l) {
    __builtin_amdgcn_global_load_lds(
        (const __attribute__((address_space(1))) unsigned int*)g,
        (__attribute__((address_space(3))) unsigned int*)l, 16, 0, 0);
}
__device__ __forceinline__ void wait_vm4() {
    asm volatile("s_waitcnt vmcnt(4)" ::: "memory");
}
__device__ __forceinline__ void wait_vm0() {
    asm volatile("s_waitcnt vmcnt(0)" ::: "memory");
}
// Guarantee all of this wave's outstanding LDS reads have completed before a
// DMA write into a just-consumed staging buffer can issue (anti-dependence the
// compiler/HW do not otherwise enforce — the R9 correctness bug).
__device__ __forceinline__ void fence_lds_reads() {
    asm volatile("s_waitcnt lgkmcnt(0)" ::: "memory");
}

// =======================================================================
// precompute: 137 blocks x 256 threads (R8 structure, verified correct)
// =======================================================================
__global__ __launch_bounds__(256) void precompute(
    const float* __restrict__ t,  const float* __restrict__ W1,
    const float* __restrict__ b1, const float* __restrict__ W2,
    const float* __restrict__ W3, u16* __restrict__ ws16, float* __restrict__ z0)
{
    __shared__ float T[16 * 264 > 256 * 20 ? 16 * 264 : 256 * 20];
    u16* W2K = ws16 + OFF_W2K;
    u16* EFK = ws16 + OFF_EFK;
    u16* W1F = ws16 + OFF_W1F;
    u16* W3F = ws16 + OFF_W3F;

    const int bid = blockIdx.x, tid = threadIdx.x;
    const int lane = tid & 63, wv = tid >> 6;
    const int m16 = lane & 15, q = lane >> 4;

    if (bid < 64) {
        const int nt = bid >> 1, bh = bid & 1;
        const int a0 = nt * 16, b0 = bh * 256;
        s16x8 afh[2], afl[2];
#pragma unroll
        for (int h = 0; h < 2; ++h)
#pragma unroll
            for (int j = 0; j < 8; ++j) {
                int i = h * 32 + q * 8 + j;
                float v = W1[(1 + i) * HH + a0 + m16];
                u16 hi = f2bf(v);
                afh[h][j] = (short)hi;
                afl[h][j] = (short)f2bf(v - bf2f(hi));
            }
#pragma unroll
        for (int bt = 0; bt < 4; ++bt) {
            int bl = wv * 64 + bt * 16;
            s16x8 bfh[2], bfl[2];
#pragma unroll
            for (int h = 0; h < 2; ++h) {
                const float* src = W3 + (b0 + bl + m16) * DD + h * 32 + q * 8;
                float4 p0 = *(const float4*)(src);
                float4 p1 = *(const float4*)(src + 4);
                float vv[8] = {p0.x,p0.y,p0.z,p0.w,p1.x,p1.y,p1.z,p1.w};
#pragma unroll
                for (int j = 0; j < 8; ++j) {
                    u16 hi = f2bf(vv[j]);
                    bfh[h][j] = (short)hi;
                    bfl[h][j] = (short)f2bf(vv[j] - bf2f(hi));
                }
            }
            f32x4 c = {0.f, 0.f, 0.f, 0.f};
#pragma unroll
            for (int h = 0; h < 2; ++h) {
                c = MFMA16(afh[h], bfh[h], c);
                c = MFMA16(afh[h], bfl[h], c);
                c = MFMA16(afl[h], bfh[h], c);
            }
#pragma unroll
            for (int r = 0; r < 4; ++r)
                T[(4 * q + r) * 264 + bl + m16] = c[r];
        }
        __syncthreads();
#pragma unroll
        for (int p = 0; p < 2; ++p) {
            int ksl = p * 4 + wv;
            int al  = m16;
            int blc = ksl * 32 + q * 8;
            const float* w2p = W2 + (a0 + al) * HH + b0 + blc;
            float4 wa = *(const float4*)(w2p), wb = *(const float4*)(w2p + 4);
            const float* glp = T + al * 264 + blc;
            s16x8 o;
            o[0]=(short)f2bf(wa.x*glp[0]); o[1]=(short)f2bf(wa.y*glp[1]);
            o[2]=(short)f2bf(wa.z*glp[2]); o[3]=(short)f2bf(wa.w*glp[3]);
            o[4]=(short)f2bf(wb.x*glp[4]); o[5]=(short)f2bf(wb.y*glp[5]);
            o[6]=(short)f2bf(wb.z*glp[6]); o[7]=(short)f2bf(wb.w*glp[7]);
            *(s16x8*)(EFK + (b0 / 32 + ksl) * 16384 + nt * 512 + lane * 8) = o;
        }
        if (bh == 0 && tid < 128) {
            int ks = tid >> 6, ln = tid & 63;
            int n  = nt * 16 + (ln & 15);
            int k0 = ks * 32 + (ln >> 4) * 8;
            s16x8 o;
#pragma unroll
            for (int j = 0; j < 8; ++j) o[j] = (short)f2bf(W1[(1 + k0 + j) * HH + n]);
            *(s16x8*)(W1F + nt * 1024 + ks * 512 + ln * 8) = o;
        }
    } else if (bid < 128) {
        const int nt = (bid - 64) >> 1, kh = (bid - 64) & 1;
        const int n0 = nt * 16, k0 = kh * 256;
#pragma unroll
        for (int it = 0; it < 4; ++it) {
            int r = (tid >> 2) + it * 64;
            int c = (tid & 3) * 4;
            float4 v = *(const float4*)(W2 + (k0 + r) * HH + n0 + c);
            *(float4*)(T + r * 20 + c) = v;
        }
        __syncthreads();
#pragma unroll
        for (int p = 0; p < 2; ++p) {
            int ksl = p * 4 + wv;
            int kqx = ksl * 32 + q * 8;
            s16x8 o;
#pragma unroll
            for (int j = 0; j < 8; ++j) o[j] = (short)f2bf(T[(kqx + j) * 20 + m16]);
            *(s16x8*)(W2K + (k0 / 32 + ksl) * 16384 + nt * 512 + lane * 8) = o;
        }
    } else if (bid < 136) {
        const int ot = (bid - 128) >> 1, kh = (bid - 128) & 1;
        const int o0 = ot * 16, k0 = kh * 256;
#pragma unroll
        for (int it = 0; it < 4; ++it) {
            int r = (tid >> 2) + it * 64;
            int c = (tid & 3) * 4;
            float4 v = *(const float4*)(W3 + (k0 + r) * DD + o0 + c);
            *(float4*)(T + r * 20 + c) = v;
        }
        __syncthreads();
#pragma unroll
        for (int p = 0; p < 2; ++p) {
            int ksl = p * 4 + wv;
            int kqx = ksl * 32 + q * 8;
            s16x8 o;
#pragma unroll
            for (int j = 0; j < 8; ++j) o[j] = (short)f2bf(T[(kqx + j) * 20 + m16]);
            *(s16x8*)(W3F + ot * 8192 + (k0 / 32 + ksl) * 512 + lane * 8) = o;
        }
    } else {
        for (int n = tid; n < HH; n += 256)
            z0[n] = b1[n] + t[0] * W1[n];
    }
}

// =======================================================================
// cnf_main: 512 blocks x 256 threads (4 waves), 16 rows/block
//   barrier-free DMA K-loops; lgkm fences guard buffer reuse (R9 fix)
// =======================================================================
__global__ __launch_bounds__(TPB) void cnf_main(
    const float* __restrict__ x,  const u16* __restrict__ ws16,
    const float* __restrict__ z0, const float* __restrict__ b2,
    const float* __restrict__ b3, float* __restrict__ out)
{
    __shared__ u16 h1s[MROWS * LP];     // h1 (d1 source)
    __shared__ u16 h2s[MROWS * LP];     // xs overlay -> h2
    __shared__ u16 stg[2][8192];        // 2 x 16KB DMA buffers (wave-private 4KB regions)
    __shared__ float z0s[HH];
    __shared__ float b2s[HH];
    __shared__ float b3s[DD];
    __shared__ float divacc[4][MROWS];

    const u16* W2K = ws16 + OFF_W2K;
    const u16* EFK = ws16 + OFF_EFK;
    const u16* W1F = ws16 + OFF_W1F;
    const u16* W3F = ws16 + OFF_W3F;

    const int tid  = threadIdx.x;
    const int lane = tid & 63;
    const int w    = tid >> 6;        // wave 0..3
    const int m16  = lane & 15;
    const int q    = lane >> 4;
    const int kq   = q * 8;
    const int r0   = blockIdx.x * MROWS;

    u16* xs = h2s;                    // x tile (pitch 72) dead after phase 1

    // ---- stage x + biases ----
    for (int idx = tid; idx < MROWS * DD; idx += TPB) {
        int r = idx >> 6, c = idx & 63;
        xs[r * 72 + c] = f2bf(x[(r0 + r) * (DD + 1) + c]);
    }
    for (int n = tid; n < HH; n += TPB) { z0s[n] = z0[n]; b2s[n] = b2[n]; }
    if (tid < DD) b3s[tid] = b3[tid];

    // W1 frags for the wave's 8 phase-1 n-tiles (register path, small)
    s16x8 b1f[8][2];
#pragma unroll
    for (int j = 0; j < 8; ++j) {
        const u16* bb = W1F + (w * 8 + j) * 1024 + lane * 8;
        b1f[j][0] = *(const s16x8*)(bb);
        b1f[j][1] = *(const s16x8*)(bb + 512);
    }
    __syncthreads();   // #1: xs, z0s ready

    // ---- phase 1: h1 = tanh([t,x]@W1 + z0), K=64; wave covers tiles 8w..8w+7 ----
    {
        s16x8 xa0 = *(const s16x8*)(xs + m16 * 72 + kq);
        s16x8 xa1 = *(const s16x8*)(xs + m16 * 72 + 32 + kq);
#pragma unroll
        for (int j = 0; j < 8; ++j) {
            f32x4 c = {0.f, 0.f, 0.f, 0.f};
            c = MFMA16(xa0, b1f[j][0], c);
            c = MFMA16(xa1, b1f[j][1], c);
            int col = (w * 8 + j) * 16 + m16;
#pragma unroll
            for (int i = 0; i < 4; ++i)
                h1s[(4 * q + i) * LP + col] = f2bf(fast_tanh(c[i] + z0s[col]));
        }
    }
    __syncthreads();   // #2: h1s published (xs reads complete)

    // ---- phase 2: h2 = tanh(h1@W2 + b2); two group passes of 4 n-tiles ----
    {
        const u16* abase = h1s + m16 * LP + kq;
        u16* my0 = stg[0] + w * 2048;         // wave-private 4KB regions
        u16* my1 = stg[1] + w * 2048;
#pragma unroll
        for (int g = 0; g < 2; ++g) {
            const u16* wbase = W2K + (g * 16 + w * 4) * 512 + lane * 8;
            fence_lds_reads();                // buffers last read earlier: drain
#pragma unroll
            for (int j = 0; j < 4; ++j) gll(wbase + j * 512,         my0 + j * 512);
#pragma unroll
            for (int j = 0; j < 4; ++j) gll(wbase + 16384 + j * 512, my1 + j * 512);
            f32x4 acc[4];
#pragma unroll
            for (int j = 0; j < 4; ++j) acc[j] = f32x4{0.f,0.f,0.f,0.f};
#pragma unroll 4
            for (int c = 0; c < 16; ++c) {
                if (c < 15) wait_vm4(); else wait_vm0();
                u16* sb = (c & 1) ? my1 : my0;
                s16x8 bf0 = *(const s16x8*)(sb +        lane * 8);
                s16x8 bf1 = *(const s16x8*)(sb +  512 + lane * 8);
                s16x8 bf2 = *(const s16x8*)(sb + 1024 + lane * 8);
                s16x8 bf3 = *(const s16x8*)(sb + 1536 + lane * 8);
                s16x8 af  = *(const s16x8*)(abase + c * 32);
                acc[0] = MFMA16(af, bf0, acc[0]);
                acc[1] = MFMA16(af, bf1, acc[1]);
                acc[2] = MFMA16(af, bf2, acc[2]);
                acc[3] = MFMA16(af, bf3, acc[3]);
                if (c < 14) {
                    fence_lds_reads();        // sb's ds_reads retired before DMA reuse
                    const u16* src = wbase + (c + 2) * 16384;
#pragma unroll
                    for (int j = 0; j < 4; ++j) gll(src + j * 512, sb + j * 512);
                }
            }
            // epilogue: tanh -> h2s (wave-own cols; h2s-as-xs is dead)
#pragma unroll
            for (int j = 0; j < 4; ++j) {
                int col = (g * 16 + w * 4 + j) * 16 + m16;
#pragma unroll
                for (int i = 0; i < 4; ++i)
                    h2s[(4 * q + i) * LP + col] = f2bf(fast_tanh(acc[j][i] + b2s[col]));
            }
        }
    }
    __syncthreads();   // #3: h2s published

    // ---- phase 3: dx = h2@W3 + b3; wave w -> output tile ot = w ----
    {
        const u16* ap = h2s + m16 * LP + kq;
        const u16* bp = W3F + w * 8192 + lane * 8;
        s16x8 W3r[4];
#pragma unroll
        for (int k = 0; k < 4; ++k) W3r[k] = *(const s16x8*)(bp + k * 512);
        f32x4 cA = {0.f,0.f,0.f,0.f}, cB = {0.f,0.f,0.f,0.f};
#pragma unroll
        for (int c = 0; c < 16; ++c) {
            s16x8 f = *(const s16x8*)(ap + c * 32);
            const int sl = c & 3;
            if (c & 1) cB = MFMA16(f, W3r[sl], cB);
            else       cA = MFMA16(f, W3r[sl], cA);
            if (c < 12) W3r[sl] = *(const s16x8*)(bp + (c + 4) * 512);
        }
        f32x4 c3 = cA + cB;
        int o = w * 16 + m16;
#pragma unroll
        for (int i = 0; i < 4; ++i)
            out[(r0 + 4 * q + i) * (DD + 1) + o] = c3[i] + b3s[o];
    }

    // ---- phase 4: M = d2@Ef (d2 on the fly from h2s); div = sum d1 .* M ----
    {
        const u16* abase = h2s + m16 * LP + kq;
        u16* my0 = stg[0] + w * 2048;
        u16* my1 = stg[1] + w * 2048;
        float dpart[4] = {0.f, 0.f, 0.f, 0.f};
#pragma unroll
        for (int g = 0; g < 2; ++g) {
            const u16* ebase = EFK + (g * 16 + w * 4) * 512 + lane * 8;
            fence_lds_reads();                // buffers last read in phase 2 / prev g
#pragma unroll
            for (int j = 0; j < 4; ++j) gll(ebase + j * 512,         my0 + j * 512);
#pragma unroll
            for (int j = 0; j < 4; ++j) gll(ebase + 16384 + j * 512, my1 + j * 512);
            f32x4 acc[4];
#pragma unroll
            for (int j = 0; j < 4; ++j) acc[j] = f32x4{0.f,0.f,0.f,0.f};
#pragma unroll 4
            for (int c = 0; c < 16; ++c) {
                if (c < 15) wait_vm4(); else wait_vm0();
                u16* sb = (c & 1) ? my1 : my0;
                s16x8 bf0 = *(const s16x8*)(sb +        lane * 8);
                s16x8 bf1 = *(const s16x8*)(sb +  512 + lane * 8);
                s16x8 bf2 = *(const s16x8*)(sb + 1024 + lane * 8);
                s16x8 bf3 = *(const s16x8*)(sb + 1536 + lane * 8);
                s16x8 hf  = *(const s16x8*)(abase + c * 32);
                s16x8 af;
#pragma unroll
                for (int jj = 0; jj < 8; ++jj) {
                    float f = bf2f((u16)hf[jj]);
                    af[jj] = (short)f2bf(1.0f - f * f);
                }
                acc[0] = MFMA16(af, bf0, acc[0]);
                acc[1] = MFMA16(af, bf1, acc[1]);
                acc[2] = MFMA16(af, bf2, acc[2]);
                acc[3] = MFMA16(af, bf3, acc[3]);
                if (c < 14) {
                    fence_lds_reads();        // sb's ds_reads retired before DMA reuse
                    const u16* src = ebase + (c + 2) * 16384;
#pragma unroll
                    for (int j = 0; j < 4; ++j) gll(src + j * 512, sb + j * 512);
                }
            }
            // epilogue: multiply by d1 (from h1s), accumulate
#pragma unroll
            for (int j = 0; j < 4; ++j) {
                int col = (g * 16 + w * 4 + j) * 16 + m16;
#pragma unroll
                for (int i = 0; i < 4; ++i) {
                    float h1v = bf2f(h1s[(4 * q + i) * LP + col]);
                    dpart[i] += (1.0f - h1v * h1v) * acc[j][i];
                }
            }
        }
        // reduce over the 16 lanes (m16) sharing each row
#pragma unroll
        for (int i = 0; i < 4; ++i) {
            float v = dpart[i];
            v += __shfl_xor(v, 1, 64);
            v += __shfl_xor(v, 2, 64);
            v += __shfl_xor(v, 4, 64);
            v += __shfl_xor(v, 8, 64);
            if (m16 == 0) divacc[w][4 * q + i] = v;
        }
    }
    __syncthreads();   // #4

    if (tid < MROWS) {
        float s = divacc[0][tid] + divacc[1][tid] + divacc[2][tid] + divacc[3][tid];
        out[(r0 + tid) * (DD + 1) + DD] = s;
    }
}

extern "C" void kernel_launch(void* const* d_in, const int* in_sizes, int n_in,
                              void* d_out, int out_size, void* d_ws, size_t ws_size,
                              hipStream_t stream) {
    const float* t  = (const float*)d_in[0];
    const float* x  = (const float*)d_in[1];
    const float* W1 = (const float*)d_in[2];
    const float* b1 = (const float*)d_in[3];
    const float* W2 = (const float*)d_in[4];
    const float* b2 = (const float*)d_in[5];
    const float* W3 = (const float*)d_in[6];
    const float* b3 = (const float*)d_in[7];
    float* out = (float*)d_out;

    u16*   ws16 = (u16*)d_ws;
    float* z0   = (float*)((char*)d_ws + OFF_Z0B);

    precompute<<<137, 256, 0, stream>>>(t, W1, b1, W2, W3, ws16, z0);
    cnf_main<<<8192 / MROWS, TPB, 0, stream>>>(x, ws16, z0, b2, b3, out);
}

// Round 11
// 96.824 us; speedup vs baseline: 1.0769x; 1.0769x over previous
//
#include <hip/hip_runtime.h>

#define HH 512
#define DD 64
#define MROWS 32
#define TPB 512
#define LP 520            // u16 pitch for 32x512 LDS tiles

typedef unsigned short u16;
typedef short s16x8 __attribute__((ext_vector_type(8)));   // 8 bf16 = 4 VGPRs
typedef float f32x4 __attribute__((ext_vector_type(4)));

#define MFMA16(A,B,C) __builtin_amdgcn_mfma_f32_16x16x32_bf16((A),(B),(C),0,0,0)

// ---- workspace layout (u16 element offsets) ----
// W2K/EFK: k-major chunks: addr = chunk*16384 + nt*512 + lane*8
//   value[j] = M[k][n], k = chunk*32 + (lane>>4)*8 + j, n = nt*16 + (lane&15)
//   (W2K: M=W2 ; EFK: M[b][a] = W2[a][b]*G[a][b], n-dim=a, k-dim=b)
// W1F: per-tile fragment-linear: nt*1024 + ks*512 + lane*8 (K=64)
// W3F: per-tile fragment-linear: ot*8192 + ks*512 + lane*8 (K=512)
#define OFF_W2K  0
#define OFF_EFK  262144
#define OFF_W1F  524288
#define OFF_W3F  557056
#define OFF_Z0B  (589824 * 2)     // byte offset of z0 (f32[512])

__device__ __forceinline__ u16 f2bf(float f) {
    unsigned u = __builtin_bit_cast(unsigned, f);
    u += 0x7fffu + ((u >> 16) & 1u);
    return (u16)(u >> 16);
}
__device__ __forceinline__ float bf2f(u16 h) {
    return __builtin_bit_cast(float, (unsigned)h << 16);
}
__device__ __forceinline__ float fast_tanh(float x) {
    float e = __expf(2.0f * x);
    return 1.0f - 2.0f * __builtin_amdgcn_rcpf(e + 1.0f);
}
__device__ __forceinline__ void gll(const u16* g, u16* l) {
    __builtin_amdgcn_global_load_lds(
        (const __attribute__((address_space(1))) unsigned int*)g,
        (__attribute__((address_space(3))) unsigned int*)l, 16, 0, 0);
}
__device__ __forceinline__ void wait_vm4() {
    asm volatile("s_waitcnt vmcnt(4)" ::: "memory");
}
__device__ __forceinline__ void wait_vm0() {
    asm volatile("s_waitcnt vmcnt(0)" ::: "memory");
}
__device__ __forceinline__ void fence_lds_reads() {
    asm volatile("s_waitcnt lgkmcnt(0)" ::: "memory");
}

// =======================================================================
// precompute: 137 blocks x 256 threads (R10 verbatim — verified correct)
// =======================================================================
__global__ __launch_bounds__(256) void precompute(
    const float* __restrict__ t,  const float* __restrict__ W1,
    const float* __restrict__ b1, const float* __restrict__ W2,
    const float* __restrict__ W3, u16* __restrict__ ws16, float* __restrict__ z0)
{
    __shared__ float T[16 * 264 > 256 * 20 ? 16 * 264 : 256 * 20];
    u16* W2K = ws16 + OFF_W2K;
    u16* EFK = ws16 + OFF_EFK;
    u16* W1F = ws16 + OFF_W1F;
    u16* W3F = ws16 + OFF_W3F;

    const int bid = blockIdx.x, tid = threadIdx.x;
    const int lane = tid & 63, wv = tid >> 6;
    const int m16 = lane & 15, q = lane >> 4;

    if (bid < 64) {
        const int nt = bid >> 1, bh = bid & 1;
        const int a0 = nt * 16, b0 = bh * 256;
        s16x8 afh[2], afl[2];
#pragma unroll
        for (int h = 0; h < 2; ++h)
#pragma unroll
            for (int j = 0; j < 8; ++j) {
                int i = h * 32 + q * 8 + j;
                float v = W1[(1 + i) * HH + a0 + m16];
                u16 hi = f2bf(v);
                afh[h][j] = (short)hi;
                afl[h][j] = (short)f2bf(v - bf2f(hi));
            }
#pragma unroll
        for (int bt = 0; bt < 4; ++bt) {
            int bl = wv * 64 + bt * 16;
            s16x8 bfh[2], bfl[2];
#pragma unroll
            for (int h = 0; h < 2; ++h) {
                const float* src = W3 + (b0 + bl + m16) * DD + h * 32 + q * 8;
                float4 p0 = *(const float4*)(src);
                float4 p1 = *(const float4*)(src + 4);
                float vv[8] = {p0.x,p0.y,p0.z,p0.w,p1.x,p1.y,p1.z,p1.w};
#pragma unroll
                for (int j = 0; j < 8; ++j) {
                    u16 hi = f2bf(vv[j]);
                    bfh[h][j] = (short)hi;
                    bfl[h][j] = (short)f2bf(vv[j] - bf2f(hi));
                }
            }
            f32x4 c = {0.f, 0.f, 0.f, 0.f};
#pragma unroll
            for (int h = 0; h < 2; ++h) {
                c = MFMA16(afh[h], bfh[h], c);
                c = MFMA16(afh[h], bfl[h], c);
                c = MFMA16(afl[h], bfh[h], c);
            }
#pragma unroll
            for (int r = 0; r < 4; ++r)
                T[(4 * q + r) * 264 + bl + m16] = c[r];
        }
        __syncthreads();
#pragma unroll
        for (int p = 0; p < 2; ++p) {
            int ksl = p * 4 + wv;
            int al  = m16;
            int blc = ksl * 32 + q * 8;
            const float* w2p = W2 + (a0 + al) * HH + b0 + blc;
            float4 wa = *(const float4*)(w2p), wb = *(const float4*)(w2p + 4);
            const float* glp = T + al * 264 + blc;
            s16x8 o;
            o[0]=(short)f2bf(wa.x*glp[0]); o[1]=(short)f2bf(wa.y*glp[1]);
            o[2]=(short)f2bf(wa.z*glp[2]); o[3]=(short)f2bf(wa.w*glp[3]);
            o[4]=(short)f2bf(wb.x*glp[4]); o[5]=(short)f2bf(wb.y*glp[5]);
            o[6]=(short)f2bf(wb.z*glp[6]); o[7]=(short)f2bf(wb.w*glp[7]);
            *(s16x8*)(EFK + (b0 / 32 + ksl) * 16384 + nt * 512 + lane * 8) = o;
        }
        if (bh == 0 && tid < 128) {
            int ks = tid >> 6, ln = tid & 63;
            int n  = nt * 16 + (ln & 15);
            int k0 = ks * 32 + (ln >> 4) * 8;
            s16x8 o;
#pragma unroll
            for (int j = 0; j < 8; ++j) o[j] = (short)f2bf(W1[(1 + k0 + j) * HH + n]);
            *(s16x8*)(W1F + nt * 1024 + ks * 512 + ln * 8) = o;
        }
    } else if (bid < 128) {
        const int nt = (bid - 64) >> 1, kh = (bid - 64) & 1;
        const int n0 = nt * 16, k0 = kh * 256;
#pragma unroll
        for (int it = 0; it < 4; ++it) {
            int r = (tid >> 2) + it * 64;
            int c = (tid & 3) * 4;
            float4 v = *(const float4*)(W2 + (k0 + r) * HH + n0 + c);
            *(float4*)(T + r * 20 + c) = v;
        }
        __syncthreads();
#pragma unroll
        for (int p = 0; p < 2; ++p) {
            int ksl = p * 4 + wv;
            int kqx = ksl * 32 + q * 8;
            s16x8 o;
#pragma unroll
            for (int j = 0; j < 8; ++j) o[j] = (short)f2bf(T[(kqx + j) * 20 + m16]);
            *(s16x8*)(W2K + (k0 / 32 + ksl) * 16384 + nt * 512 + lane * 8) = o;
        }
    } else if (bid < 136) {
        const int ot = (bid - 128) >> 1, kh = (bid - 128) & 1;
        const int o0 = ot * 16, k0 = kh * 256;
#pragma unroll
        for (int it = 0; it < 4; ++it) {
            int r = (tid >> 2) + it * 64;
            int c = (tid & 3) * 4;
            float4 v = *(const float4*)(W3 + (k0 + r) * DD + o0 + c);
            *(float4*)(T + r * 20 + c) = v;
        }
        __syncthreads();
#pragma unroll
        for (int p = 0; p < 2; ++p) {
            int ksl = p * 4 + wv;
            int kqx = ksl * 32 + q * 8;
            s16x8 o;
#pragma unroll
            for (int j = 0; j < 8; ++j) o[j] = (short)f2bf(T[(kqx + j) * 20 + m16]);
            *(s16x8*)(W3F + ot * 8192 + (k0 / 32 + ksl) * 512 + lane * 8) = o;
        }
    } else {
        for (int n = tid; n < HH; n += 256)
            z0[n] = b1[n] + t[0] * W1[n];
    }
}

// =======================================================================
// cnf_main: 256 blocks x 512 threads (8 waves), 32 rows/block, 1 block/CU
//   R10's wave-private DMA pipeline, halved per-CU traffic, single pass
// =======================================================================
__global__ __launch_bounds__(TPB) void cnf_main(
    const float* __restrict__ x,  const u16* __restrict__ ws16,
    const float* __restrict__ z0, const float* __restrict__ b2,
    const float* __restrict__ b3, float* __restrict__ out)
{
    __shared__ u16 h1s[MROWS * LP];     // 33.3 KB
    __shared__ u16 h2s[MROWS * LP];     // xs overlay -> h2 (d2 on the fly)
    __shared__ u16 stg[2][16384];       // 2 x 32KB; wave w region = + w*2048
    __shared__ float z0s[HH];
    __shared__ float b2s[HH];
    __shared__ float b3s[DD];
    __shared__ float divacc[8][MROWS];

    const u16* W2K = ws16 + OFF_W2K;
    const u16* EFK = ws16 + OFF_EFK;
    const u16* W1F = ws16 + OFF_W1F;
    const u16* W3F = ws16 + OFF_W3F;

    const int tid  = threadIdx.x;
    const int lane = tid & 63;
    const int w    = tid >> 6;        // wave 0..7; owns n-tiles 4w..4w+3
    const int m16  = lane & 15;
    const int q    = lane >> 4;
    const int kq   = q * 8;
    const int r0   = blockIdx.x * MROWS;

    u16* xs = h2s;                    // x tile (pitch 72) dead after phase 1

    // ---- prestage W2 chunks 0,1 (latency hides under x staging + phase 1) ----
#pragma unroll
    for (int j = 0; j < 4; ++j)
        gll(W2K + (4 * w + j) * 512 + lane * 8,         stg[0] + w * 2048 + j * 512);
#pragma unroll
    for (int j = 0; j < 4; ++j)
        gll(W2K + 16384 + (4 * w + j) * 512 + lane * 8, stg[1] + w * 2048 + j * 512);

    // ---- stage x + biases ----
    for (int idx = tid; idx < MROWS * DD; idx += TPB) {
        int r = idx >> 6, c = idx & 63;
        xs[r * 72 + c] = f2bf(x[(r0 + r) * (DD + 1) + c]);
    }
    z0s[tid] = z0[tid];               // TPB == HH
    b2s[tid] = b2[tid];
    if (tid < DD) b3s[tid] = b3[tid];

    // W1 frags for the wave's 4 n-tiles (register path, small)
    s16x8 b1f[4][2];
#pragma unroll
    for (int j = 0; j < 4; ++j) {
        const u16* bb = W1F + (4 * w + j) * 1024 + lane * 8;
        b1f[j][0] = *(const s16x8*)(bb);
        b1f[j][1] = *(const s16x8*)(bb + 512);
    }
    __syncthreads();   // #1: xs, z0s ready (drains prestage — arrival, fine)

    float d1reg[2][4][4];             // d1 = 1-h1^2, kept in regs for phase 4

    // ---- phase 1: h1 = tanh([t,x]@W1 + z0), K=64; 2 rowtiles x 4 ntiles ----
    {
        s16x8 xa[2][2];
#pragma unroll
        for (int rt = 0; rt < 2; ++rt) {
            xa[rt][0] = *(const s16x8*)(xs + (rt * 16 + m16) * 72 + kq);
            xa[rt][1] = *(const s16x8*)(xs + (rt * 16 + m16) * 72 + 32 + kq);
        }
#pragma unroll
        for (int j = 0; j < 4; ++j) {
            int col = (4 * w + j) * 16 + m16;
#pragma unroll
            for (int rt = 0; rt < 2; ++rt) {
                f32x4 c = {0.f, 0.f, 0.f, 0.f};
                c = MFMA16(xa[rt][0], b1f[j][0], c);
                c = MFMA16(xa[rt][1], b1f[j][1], c);
#pragma unroll
                for (int i = 0; i < 4; ++i) {
                    float hv = fast_tanh(c[i] + z0s[col]);
                    h1s[(rt * 16 + 4 * q + i) * LP + col] = f2bf(hv);
                    d1reg[rt][j][i] = 1.0f - hv * hv;
                }
            }
        }
    }
    __syncthreads();   // #2: h1s published (xs reads complete)

    // ---- phase 2: h2 = tanh(h1@W2 + b2); single 16-chunk DMA K-loop ----
    f32x4 acc[2][4];
#pragma unroll
    for (int rt = 0; rt < 2; ++rt)
#pragma unroll
        for (int j = 0; j < 4; ++j) acc[rt][j] = f32x4{0.f,0.f,0.f,0.f};
    {
        const u16* ap0 = h1s + m16 * LP + kq;
        const u16* ap1 = h1s + (16 + m16) * LP + kq;
#pragma unroll 4
        for (int c = 0; c < 16; ++c) {
            if (c < 15) wait_vm4(); else wait_vm0();
            u16* sb = stg[c & 1] + w * 2048;
            s16x8 bf0 = *(const s16x8*)(sb +        lane * 8);
            s16x8 bf1 = *(const s16x8*)(sb +  512 + lane * 8);
            s16x8 bf2 = *(const s16x8*)(sb + 1024 + lane * 8);
            s16x8 bf3 = *(const s16x8*)(sb + 1536 + lane * 8);
            s16x8 f0  = *(const s16x8*)(ap0 + c * 32);
            s16x8 f1  = *(const s16x8*)(ap1 + c * 32);
            acc[0][0] = MFMA16(f0, bf0, acc[0][0]);
            acc[1][0] = MFMA16(f1, bf0, acc[1][0]);
            acc[0][1] = MFMA16(f0, bf1, acc[0][1]);
            acc[1][1] = MFMA16(f1, bf1, acc[1][1]);
            acc[0][2] = MFMA16(f0, bf2, acc[0][2]);
            acc[1][2] = MFMA16(f1, bf2, acc[1][2]);
            acc[0][3] = MFMA16(f0, bf3, acc[0][3]);
            acc[1][3] = MFMA16(f1, bf3, acc[1][3]);
            if (c < 14) {
                fence_lds_reads();        // sb's ds_reads retired before DMA reuse
                const u16* src = W2K + (c + 2) * 16384 + 4 * w * 512 + lane * 8;
#pragma unroll
                for (int j = 0; j < 4; ++j) gll(src + j * 512, sb + j * 512);
            }
        }
    }

    // ---- prestage Ef chunks 0,1 (arrive by barrier #3 drain) ----
    fence_lds_reads();
#pragma unroll
    for (int j = 0; j < 4; ++j)
        gll(EFK + (4 * w + j) * 512 + lane * 8,         stg[0] + w * 2048 + j * 512);
#pragma unroll
    for (int j = 0; j < 4; ++j)
        gll(EFK + 16384 + (4 * w + j) * 512 + lane * 8, stg[1] + w * 2048 + j * 512);

    // ---- phase-2 epilogue: tanh -> h2s (xs region dead) ----
#pragma unroll
    for (int j = 0; j < 4; ++j) {
        int col = (4 * w + j) * 16 + m16;
#pragma unroll
        for (int rt = 0; rt < 2; ++rt)
#pragma unroll
            for (int i = 0; i < 4; ++i)
                h2s[(rt * 16 + 4 * q + i) * LP + col] =
                    f2bf(fast_tanh(acc[rt][j][i] + b2s[col]));
    }
    __syncthreads();   // #3: h2s published (also drains Ef prestage)

    // ---- phase 3: dx = h2@W3 + b3; 8 waves = 2 rowtiles x 4 o-tiles ----
    {
        const int rowt = w >> 2, ot = w & 3;
        const u16* ap = h2s + (rowt * 16 + m16) * LP + kq;
        const u16* bp = W3F + ot * 8192 + lane * 8;
        s16x8 W3r[4];
#pragma unroll
        for (int k = 0; k < 4; ++k) W3r[k] = *(const s16x8*)(bp + k * 512);
        f32x4 cA = {0.f,0.f,0.f,0.f}, cB = {0.f,0.f,0.f,0.f};
#pragma unroll
        for (int c = 0; c < 16; ++c) {
            s16x8 f = *(const s16x8*)(ap + c * 32);
            const int sl = c & 3;
            if (c & 1) cB = MFMA16(f, W3r[sl], cB);
            else       cA = MFMA16(f, W3r[sl], cA);
            if (c < 12) W3r[sl] = *(const s16x8*)(bp + (c + 4) * 512);
        }
        f32x4 c3 = cA + cB;
        int o = ot * 16 + m16;
#pragma unroll
        for (int i = 0; i < 4; ++i)
            out[(r0 + rowt * 16 + 4 * q + i) * (DD + 1) + o] = c3[i] + b3s[o];
    }

    // ---- phase 4: M = d2@Ef (d2 on the fly); div = sum d1 .* M ----
    {
        f32x4 g[2][4];
#pragma unroll
        for (int rt = 0; rt < 2; ++rt)
#pragma unroll
            for (int j = 0; j < 4; ++j) g[rt][j] = f32x4{0.f,0.f,0.f,0.f};
        const u16* ap0 = h2s + m16 * LP + kq;
        const u16* ap1 = h2s + (16 + m16) * LP + kq;
#pragma unroll 4
        for (int c = 0; c < 16; ++c) {
            if (c < 15) wait_vm4(); else wait_vm0();
            u16* sb = stg[c & 1] + w * 2048;
            s16x8 ef0 = *(const s16x8*)(sb +        lane * 8);
            s16x8 ef1 = *(const s16x8*)(sb +  512 + lane * 8);
            s16x8 ef2 = *(const s16x8*)(sb + 1024 + lane * 8);
            s16x8 ef3 = *(const s16x8*)(sb + 1536 + lane * 8);
            s16x8 hf0 = *(const s16x8*)(ap0 + c * 32);
            s16x8 hf1 = *(const s16x8*)(ap1 + c * 32);
            s16x8 af0, af1;
#pragma unroll
            for (int jj = 0; jj < 8; ++jj) {
                float v0 = bf2f((u16)hf0[jj]);
                float v1 = bf2f((u16)hf1[jj]);
                af0[jj] = (short)f2bf(1.0f - v0 * v0);
                af1[jj] = (short)f2bf(1.0f - v1 * v1);
            }
            g[0][0] = MFMA16(af0, ef0, g[0][0]);
            g[1][0] = MFMA16(af1, ef0, g[1][0]);
            g[0][1] = MFMA16(af0, ef1, g[0][1]);
            g[1][1] = MFMA16(af1, ef1, g[1][1]);
            g[0][2] = MFMA16(af0, ef2, g[0][2]);
            g[1][2] = MFMA16(af1, ef2, g[1][2]);
            g[0][3] = MFMA16(af0, ef3, g[0][3]);
            g[1][3] = MFMA16(af1, ef3, g[1][3]);
            if (c < 14) {
                fence_lds_reads();
                const u16* src = EFK + (c + 2) * 16384 + 4 * w * 512 + lane * 8;
#pragma unroll
                for (int j = 0; j < 4; ++j) gll(src + j * 512, sb + j * 512);
            }
        }
        // combine with d1, lane-reduce over m16
#pragma unroll
        for (int rt = 0; rt < 2; ++rt)
#pragma unroll
            for (int i = 0; i < 4; ++i) {
                float v = d1reg[rt][0][i] * g[rt][0][i]
                        + d1reg[rt][1][i] * g[rt][1][i]
                        + d1reg[rt][2][i] * g[rt][2][i]
                        + d1reg[rt][3][i] * g[rt][3][i];
                v += __shfl_xor(v, 1, 64);
                v += __shfl_xor(v, 2, 64);
                v += __shfl_xor(v, 4, 64);
                v += __shfl_xor(v, 8, 64);
                if (m16 == 0) divacc[w][rt * 16 + 4 * q + i] = v;
            }
    }
    __syncthreads();   // #4

    if (tid < MROWS) {
        float s = 0.0f;
#pragma unroll
        for (int ww = 0; ww < 8; ++ww) s += divacc[ww][tid];
        out[(r0 + tid) * (DD + 1) + DD] = s;
    }
}

extern "C" void kernel_launch(void* const* d_in, const int* in_sizes, int n_in,
                              void* d_out, int out_size, void* d_ws, size_t ws_size,
                              hipStream_t stream) {
    const float* t  = (const float*)d_in[0];
    const float* x  = (const float*)d_in[1];
    const float* W1 = (const float*)d_in[2];
    const float* b1 = (const float*)d_in[3];
    const float* W2 = (const float*)d_in[4];
    const float* b2 = (const float*)d_in[5];
    const float* W3 = (const float*)d_in[6];
    const float* b3 = (const float*)d_in[7];
    float* out = (float*)d_out;

    u16*   ws16 = (u16*)d_ws;
    float* z0   = (float*)((char*)d_ws + OFF_Z0B);

    precompute<<<137, 256, 0, stream>>>(t, W1, b1, W2, W3, ws16, z0);
    cnf_main<<<8192 / MROWS, TPB, 0, stream>>>(x, ws16, z0, b2, b3, out);
}